// Round 7
// baseline (247.398 us; speedup 1.0000x reference)
//
#include <hip/hip_runtime.h>
#include <hip/hip_fp16.h>
#include <math.h>

#define N_NODES 50000
#define N_EDGES 800000
#define F_IN    128
#define D_HID   96
#define NHEAD   8
#define DH      12
#define N_CLS   40
#define NEG_SLOPE 0.2f

#define NPART   (N_NODES / 8)        // 6250 dst nodes per XCD group
#define NWCHUNK 256                  // edge chunks per group
#define ECHUNK  (N_EDGES / NWCHUNK)  // 3125 edges per chunk
#define NHISTB  (8 * NWCHUNK)        // 2048 hist/fill blocks

#define GBM 64                       // gemm rows per block
#define NGB ((N_NODES + GBM - 1) / GBM)   // 782

typedef _Float16 f16x8 __attribute__((ext_vector_type(8)));
typedef float    f32x4 __attribute__((ext_vector_type(4)));

// ---------------- zero cnt (custom: runtime fillBuffer is ~40us for 200KB) ----------------
__global__ __launch_bounds__(256) void zero_kernel(int4* __restrict__ p, int n4) {
    int i = blockIdx.x * blockDim.x + threadIdx.x;
    if (i < n4) p[i] = make_int4(0, 0, 0, 0);
}

// ---------------- MFMA GEMM core: H = A[M,K] @ W[K,96] (fp16 in, fp32 acc) ------------
// Block = 256 thr = 4 waves; wave w computes rows [bid*64 + w*16, +16) x all 96 cols via
// 6 x mfma_f32_16x16x32_f16. Fragment layout (verified m89): A row=lane&15,
// k=8*(lane>>4)+j; B col=lane&15, same k; D col=lane&15, row=4*(lane>>4)+r.
// Epilogue: acc -> LDS H-tile (static indices only) -> alpha dots + fp16 H store.
__device__ __forceinline__ void gemm_alpha_mfma_body(
    const float* __restrict__ A, const float* __restrict__ W,
    const float* __restrict__ asrc, const float* __restrict__ adst,
    __half* __restrict__ Hout, float* __restrict__ aS, float* __restrict__ aD,
    int M, int K, int bid,
    _Float16 (*Xs)[40], _Float16 (*Wt)[40], _Float16 (*Hl)[104])
{
    int tid  = threadIdx.x;
    int lane = tid & 63;
    int w    = tid >> 6;
    int n0   = bid * GBM;

    f32x4 acc[6];
#pragma unroll
    for (int t = 0; t < 6; t++) acc[t] = (f32x4){0.f, 0.f, 0.f, 0.f};

    int arow = (w << 4) + (lane & 15);
    int k8   = (lane >> 4) << 3;

    for (int k0 = 0; k0 < K; k0 += 32) {
        // stage X tile 64x32 (fp32->fp16), coalesced on k
        for (int idx = tid; idx < GBM * 32; idx += 256) {
            int row = idx >> 5, kk = idx & 31;
            int gr = n0 + row;
            Xs[row][kk] = (_Float16)((gr < M) ? A[(size_t)gr * K + k0 + kk] : 0.f);
        }
        // stage W transposed: Wt[n][kk] = W[(k0+kk)*96 + n]
        for (int idx = tid; idx < 32 * D_HID; idx += 256) {
            int n = idx % D_HID, kk = idx / D_HID;
            Wt[n][kk] = (_Float16)W[(size_t)(k0 + kk) * D_HID + n];
        }
        __syncthreads();
        f16x8 av = *(const f16x8*)&Xs[arow][k8];
#pragma unroll
        for (int t = 0; t < 6; t++) {
            f16x8 bv = *(const f16x8*)&Wt[t * 16 + (lane & 15)][k8];
            acc[t] = __builtin_amdgcn_mfma_f32_16x16x32_f16(av, bv, acc[t], 0, 0, 0);
        }
        __syncthreads();
    }

    // acc -> Hl (fp16), all indices static per unrolled iteration
    {
        int rbase = (w << 4) + ((lane >> 4) << 2);
        int c     = lane & 15;
#pragma unroll
        for (int t = 0; t < 6; t++)
#pragma unroll
            for (int r = 0; r < 4; r++)
                Hl[rbase + r][t * 16 + c] = (_Float16)acc[t][r];
    }
    __syncthreads();

    // epilogue: thread (row=tid>>2, q=tid&3) owns cols [24q, 24q+24) = heads 2q, 2q+1
    int row = tid >> 2, q = tid & 3;
    int gr = n0 + row;
    if (gr < M) {
        float s_[2] = {0.f, 0.f}, d_[2] = {0.f, 0.f};
#pragma unroll
        for (int j = 0; j < 24; j++) {
            float f = (float)Hl[row][q * 24 + j];
            s_[j / 12] += f * asrc[q * 24 + j];
            d_[j / 12] += f * adst[q * 24 + j];
        }
        aS[gr * NHEAD + 2 * q]     = s_[0];
        aS[gr * NHEAD + 2 * q + 1] = s_[1];
        aD[gr * NHEAD + 2 * q]     = d_[0];
        aD[gr * NHEAD + 2 * q + 1] = d_[1];
        const uint4* src = (const uint4*)&Hl[row][q * 24];
        uint4* dst = (uint4*)(Hout + (size_t)gr * D_HID + q * 24);
        dst[0] = src[0]; dst[1] = src[1]; dst[2] = src[2];
    }
}

// ---------------- fused: hist (blocks [0,NHISTB)) + gemm0 (blocks [NHISTB,..)) --------
__global__ __launch_bounds__(256) void hist_gemm_kernel(
    const int* __restrict__ edst, int* __restrict__ cnt,
    const float* __restrict__ A, const float* __restrict__ W,
    const float* __restrict__ asrc, const float* __restrict__ adst,
    __half* __restrict__ Hout, float* __restrict__ aS, float* __restrict__ aD)
{
    __shared__ _Float16 Xs[GBM][40];
    __shared__ _Float16 Wt[D_HID][40];
    __shared__ _Float16 Hl[GBM][104];
    if (blockIdx.x < NHISTB) {
        int lo = (blockIdx.x & 7) * NPART;   // bid&7 == XCD (round-robin dispatch)
        int e0 = (blockIdx.x >> 3) * ECHUNK;
        for (int e = e0 + threadIdx.x; e < e0 + ECHUNK; e += 256) {
            int d = edst[e] - lo;
            if ((unsigned)d < (unsigned)NPART) atomicAdd(&cnt[lo + d], 1);
        }
    } else {
        gemm_alpha_mfma_body(A, W, asrc, adst, Hout, aS, aD, N_NODES, F_IN,
                             blockIdx.x - NHISTB, Xs, Wt, Hl);
    }
}

// ---------------- standalone gemm (layer 1) ----------------
__global__ __launch_bounds__(256) void gemm_alpha_kernel(
    const float* __restrict__ A, const float* __restrict__ W,
    const float* __restrict__ asrc, const float* __restrict__ adst,
    __half* __restrict__ Hout, float* __restrict__ aS, float* __restrict__ aD,
    int M, int K)
{
    __shared__ _Float16 Xs[GBM][40];
    __shared__ _Float16 Wt[D_HID][40];
    __shared__ _Float16 Hl[GBM][104];
    gemm_alpha_mfma_body(A, W, asrc, adst, Hout, aS, aD, M, K, blockIdx.x, Xs, Wt, Hl);
}

// ---------------- scans ----------------
__global__ void scan1_kernel(const int* __restrict__ cnt, int* __restrict__ incl,
                             int* __restrict__ partials, int n) {
    __shared__ int sdata[256];
    int t = threadIdx.x;
    int base = blockIdx.x * 1024 + t * 4;
    int v[4];
#pragma unroll
    for (int j = 0; j < 4; j++) { int i = base + j; v[j] = (i < n) ? cnt[i] : 0; }
    v[1] += v[0]; v[2] += v[1]; v[3] += v[2];
    sdata[t] = v[3];
    __syncthreads();
    for (int off = 1; off < 256; off <<= 1) {
        int x = (t >= off) ? sdata[t - off] : 0;
        __syncthreads();
        sdata[t] += x;
        __syncthreads();
    }
    int excl = sdata[t] - v[3];
#pragma unroll
    for (int j = 0; j < 4; j++) { int i = base + j; if (i < n) incl[i] = v[j] + excl; }
    if (t == 255) partials[blockIdx.x] = sdata[255];
}

__global__ void scan3_kernel(const int* __restrict__ cnt, int* __restrict__ incl_cursor,
                             const int* __restrict__ partials, int* __restrict__ rowptr,
                             int n, int nb) {
    int i = blockIdx.x * blockDim.x + threadIdx.x;
    if (i >= n) return;
    int myb = i >> 10;
    int psum = 0;
    for (int b = 0; b < nb; b++) psum += (b < myb) ? partials[b] : 0;
    int v = incl_cursor[i] + psum;
    rowptr[i + 1] = v;
    incl_cursor[i] = v - cnt[i];
    if (i == 0) rowptr[0] = 0;
}

__global__ __launch_bounds__(256) void fill_part_kernel(
    const int* __restrict__ esrc, const int* __restrict__ edst,
    int* __restrict__ cursor, unsigned short* __restrict__ srclist)
{
    int lo = (blockIdx.x & 7) * NPART;
    int e0 = (blockIdx.x >> 3) * ECHUNK;
    for (int e = e0 + threadIdx.x; e < e0 + ECHUNK; e += 256) {
        int d = edst[e] - lo;
        if ((unsigned)d < (unsigned)NPART) {
            int p = atomicAdd(&cursor[lo + d], 1);
            srclist[p] = (unsigned short)esrc[e];
        }
    }
}

// ---------------- GAT aggregation: 16 lanes per node (2 per head) ----------------
__device__ __forceinline__ void agg_edge(const __half* __restrict__ h, int s, int hh,
                                         float p, float* acc) {
    const uint2* hp = (const uint2*)(h + (size_t)s * D_HID + hh * 12);
    uint2 q0 = hp[0], q1 = hp[1], q2 = hp[2];
    float2 f0 = __half22float2(((const __half2*)&q0)[0]);
    float2 f1 = __half22float2(((const __half2*)&q0)[1]);
    float2 f2 = __half22float2(((const __half2*)&q1)[0]);
    float2 f3 = __half22float2(((const __half2*)&q1)[1]);
    float2 f4 = __half22float2(((const __half2*)&q2)[0]);
    float2 f5 = __half22float2(((const __half2*)&q2)[1]);
    acc[0] += p * f0.x; acc[1]  += p * f0.y;
    acc[2] += p * f1.x; acc[3]  += p * f1.y;
    acc[4] += p * f2.x; acc[5]  += p * f2.y;
    acc[6] += p * f3.x; acc[7]  += p * f3.y;
    acc[8] += p * f4.x; acc[9]  += p * f4.y;
    acc[10] += p * f5.x; acc[11] += p * f5.y;
}

// half-segment accumulate: edges [b0,b1), returns z; acc[12] accumulated
__device__ __forceinline__ float agg_half(
    const __half* __restrict__ h, const float* __restrict__ aS,
    const unsigned short* __restrict__ srclist,
    int b0, int b1, int hh, float ad, float* acc)
{
    float z = 0.f;
    int i = b0;
    for (; i + 4 <= b1; i += 4) {
        int sa = srclist[i];
        int sb = srclist[i + 1];
        int sc = srclist[i + 2];
        int sd = srclist[i + 3];
        float ea = aS[sa * NHEAD + hh] + ad;
        float eb = aS[sb * NHEAD + hh] + ad;
        float ec = aS[sc * NHEAD + hh] + ad;
        float ed = aS[sd * NHEAD + hh] + ad;
        ea = (ea > 0.f) ? ea : NEG_SLOPE * ea;
        eb = (eb > 0.f) ? eb : NEG_SLOPE * eb;
        ec = (ec > 0.f) ? ec : NEG_SLOPE * ec;
        ed = (ed > 0.f) ? ed : NEG_SLOPE * ed;
        float pa = __expf(ea);
        float pb = __expf(eb);
        float pc = __expf(ec);
        float pd = __expf(ed);
        z += (pa + pb) + (pc + pd);
        agg_edge(h, sa, hh, pa, acc);
        agg_edge(h, sb, hh, pb, acc);
        agg_edge(h, sc, hh, pc, acc);
        agg_edge(h, sd, hh, pd, acc);
    }
    for (; i < b1; i++) {
        int sa = srclist[i];
        float ea = aS[sa * NHEAD + hh] + ad;
        ea = (ea > 0.f) ? ea : NEG_SLOPE * ea;
        float pa = __expf(ea);
        z += pa;
        agg_edge(h, sa, hh, pa, acc);
    }
    return z;
}

// layer-0 aggregate -> bufY.  16 lanes/node: lane q = tid&15, head = q&7, half = q>>3.
__global__ __launch_bounds__(256) void gat_aggregate_kernel(
    const __half* __restrict__ h, const float* __restrict__ aS, const float* __restrict__ aD,
    const int* __restrict__ rowptr, const unsigned short* __restrict__ srclist,
    const float* __restrict__ bias, float* __restrict__ out)
{
    int gid  = blockIdx.x * 256 + threadIdx.x;
    int n    = gid >> 4;                 // grid exact: 50000*16 == 3125*256
    int q    = threadIdx.x & 15;
    int hh   = q & 7;
    int half = q >> 3;
    int s0 = rowptr[n], s1 = rowptr[n + 1];
    int mid = s0 + ((s1 - s0 + 1) >> 1);
    float ad = aD[n * NHEAD + hh];

    float acc[12];
#pragma unroll
    for (int j = 0; j < 12; j++) acc[j] = 0.f;
    float z = agg_half(h, aS, srclist, half ? mid : s0, half ? s1 : mid, hh, ad, acc);

    z += __shfl_xor(z, 8, 64);
#pragma unroll
    for (int j = 0; j < 12; j++) acc[j] += __shfl_xor(acc[j], 8, 64);

    if (half == 0) {
        float inv = 1.f / (z + 1e-16f);
        const float* bp = bias + hh * 12;
        float o[12];
#pragma unroll
        for (int j = 0; j < 12; j++) o[j] = acc[j] * inv + bp[j];
        float4* op = (float4*)(out + (size_t)n * D_HID + hh * 12);
        op[0] = make_float4(o[0], o[1], o[2], o[3]);
        op[1] = make_float4(o[4], o[5], o[6], o[7]);
        op[2] = make_float4(o[8], o[9], o[10], o[11]);
    }
}

// layer-1 aggregate + relu + (y @ Wout + bout) + log_softmax fused (LDS exchange;
// all register arrays statically indexed — rule #20).
#define YPAD 100
__global__ __launch_bounds__(256) void gat_aggregate_final_kernel(
    const __half* __restrict__ h, const float* __restrict__ aS, const float* __restrict__ aD,
    const int* __restrict__ rowptr, const unsigned short* __restrict__ srclist,
    const float* __restrict__ bias,
    const float* __restrict__ Wout, const float* __restrict__ bout,
    float* __restrict__ out)
{
    __shared__ float WsT[N_CLS][YPAD];   // WsT[c][r] = Wout[r*40+c]
    __shared__ float bs[N_CLS];
    __shared__ float ylds[16][YPAD];     // 16 nodes/block x 96-wide y
    for (int idx = threadIdx.x; idx < D_HID * N_CLS; idx += 256) {
        int r = idx / N_CLS, c = idx - r * N_CLS;
        WsT[c][r] = Wout[idx];
    }
    for (int idx = threadIdx.x; idx < N_CLS; idx += 256) bs[idx] = bout[idx];
    __syncthreads();

    int gid  = blockIdx.x * 256 + threadIdx.x;
    int n    = gid >> 4;
    int q    = threadIdx.x & 15;
    int hh   = q & 7;
    int half = q >> 3;
    int ln   = threadIdx.x >> 4;
    int s0 = rowptr[n], s1 = rowptr[n + 1];
    int mid = s0 + ((s1 - s0 + 1) >> 1);
    float ad = aD[n * NHEAD + hh];

    float acc[12];
#pragma unroll
    for (int j = 0; j < 12; j++) acc[j] = 0.f;
    float z = agg_half(h, aS, srclist, half ? mid : s0, half ? s1 : mid, hh, ad, acc);

    z += __shfl_xor(z, 8, 64);
#pragma unroll
    for (int j = 0; j < 12; j++) acc[j] += __shfl_xor(acc[j], 8, 64);

    if (half == 0) {
        float inv = 1.f / (z + 1e-16f);
        const float* bp = bias + hh * 12;
        float o[12];
#pragma unroll
        for (int j = 0; j < 12; j++) o[j] = fmaxf(acc[j] * inv + bp[j], 0.f);

        // publish y slice (same-wave producer/consumer: in-order DS, no barrier)
        float4* yw = (float4*)&ylds[ln][hh * 12];
        yw[0] = make_float4(o[0], o[1], o[2], o[3]);
        yw[1] = make_float4(o[4], o[5], o[6], o[7]);
        yw[2] = make_float4(o[8], o[9], o[10], o[11]);

        int c0 = hh * 5;
        float res[5];
#pragma unroll
        for (int k = 0; k < 5; k++) res[k] = bs[c0 + k];
        const float4* yr = (const float4*)&ylds[ln][0];
#pragma unroll
        for (int r4 = 0; r4 < D_HID / 4; r4++) {
            float4 yv = yr[r4];
#pragma unroll
            for (int k = 0; k < 5; k++) {
                float4 wv = *(const float4*)&WsT[c0 + k][r4 * 4];
                res[k] += yv.x * wv.x + yv.y * wv.y + yv.z * wv.z + yv.w * wv.w;
            }
        }

        float m = res[0];
#pragma unroll
        for (int k = 1; k < 5; k++) m = fmaxf(m, res[k]);
#pragma unroll
        for (int d = 1; d < 8; d <<= 1) m = fmaxf(m, __shfl_xor(m, d, 64));
        float sp = 0.f;
#pragma unroll
        for (int k = 0; k < 5; k++) sp += __expf(res[k] - m);
#pragma unroll
        for (int d = 1; d < 8; d <<= 1) sp += __shfl_xor(sp, d, 64);
        float mlg = m + __logf(sp);

        float* op = out + (size_t)n * N_CLS + c0;
#pragma unroll
        for (int k = 0; k < 5; k++) op[k] = res[k] - mlg;
    }
}

extern "C" void kernel_launch(void* const* d_in, const int* in_sizes, int n_in,
                              void* d_out, int out_size, void* d_ws, size_t ws_size,
                              hipStream_t stream)
{
    const float* x    = (const float*)d_in[0];
    const int*   esrc = (const int*)d_in[1];
    const int*   edst = (const int*)d_in[2];
    const float* W0   = (const float*)d_in[3];
    const float* as0  = (const float*)d_in[4];
    const float* ad0  = (const float*)d_in[5];
    const float* b0   = (const float*)d_in[6];
    const float* W1   = (const float*)d_in[7];
    const float* as1  = (const float*)d_in[8];
    const float* ad1  = (const float*)d_in[9];
    const float* b1   = (const float*)d_in[10];
    const float* Wout = (const float*)d_in[11];
    const float* bout = (const float*)d_in[12];
    float* out = (float*)d_out;

    char* p = (char*)d_ws;
    float* bufY   = (float*)p; p += (size_t)N_NODES * D_HID * sizeof(float);
    float* aS     = (float*)p; p += (size_t)N_NODES * NHEAD * sizeof(float);
    float* aD     = (float*)p; p += (size_t)N_NODES * NHEAD * sizeof(float);
    __half* bufH  = (__half*)p; p += (size_t)N_NODES * D_HID * sizeof(__half);
    int*   cnt    = (int*)p;   p += ((size_t)N_NODES + 16) * sizeof(int);
    int*   rowptr = (int*)p;   p += ((size_t)N_NODES + 16) * sizeof(int);
    int*   cursor = (int*)p;   p += ((size_t)N_NODES + 16) * sizeof(int);
    unsigned short* srclist = (unsigned short*)p; p += (size_t)N_EDGES * sizeof(unsigned short);
    int*   partials=(int*)p;   p += 256;

    int nscan = (N_NODES + 1023) / 1024;   // 49

    // 1. zero cnt
    zero_kernel<<<(N_NODES / 4 + 255) / 256, 256, 0, stream>>>((int4*)cnt, N_NODES / 4);
    // 2. hist (XCD-partitioned) + MFMA gemm0 fused by grid-slicing
    hist_gemm_kernel<<<NHISTB + NGB, 256, 0, stream>>>(
        edst, cnt, x, W0, as0, ad0, bufH, aS, aD);
    // 3-4. scan
    scan1_kernel<<<nscan, 256, 0, stream>>>(cnt, cursor, partials, N_NODES);
    scan3_kernel<<<(N_NODES + 255) / 256, 256, 0, stream>>>(cnt, cursor, partials, rowptr,
                                                            N_NODES, nscan);
    // 5. fill CSR
    fill_part_kernel<<<NHISTB, 256, 0, stream>>>(esrc, edst, cursor, srclist);
    // 6. layer-0 aggregate -> bufY (16 lanes/node)
    gat_aggregate_kernel<<<(N_NODES * 16) / 256, 256, 0, stream>>>(
        bufH, aS, aD, rowptr, srclist, b0, bufY);
    // 7. layer-1 MFMA gemm
    gemm_alpha_kernel<<<NGB, 256, 0, stream>>>(
        bufY, W1, as1, ad1, bufH, aS, aD, N_NODES, D_HID);
    // 8. layer-1 aggregate + relu + output linear + log_softmax -> out
    gat_aggregate_final_kernel<<<(N_NODES * 16) / 256, 256, 0, stream>>>(
        bufH, aS, aD, rowptr, srclist, b1, Wout, bout, out);
}

// Round 8
// 204.297 us; speedup vs baseline: 1.2110x; 1.2110x over previous
//
#include <hip/hip_runtime.h>
#include <hip/hip_fp16.h>
#include <math.h>

#define N_NODES 50000
#define N_EDGES 800000
#define F_IN    128
#define D_HID   96
#define NHEAD   8
#define DH      12
#define N_CLS   40
#define NEG_SLOPE 0.2f

#define NPART   (N_NODES / 8)        // 6250 dst nodes per XCD group
#define NWCHUNK 256                  // edge chunks per group
#define ECHUNK  (N_EDGES / NWCHUNK)  // 3125 edges per chunk
#define NHISTB  (8 * NWCHUNK)        // 2048 hist/fill blocks

#define GBM 64                       // gemm rows per block
#define NGB ((N_NODES + GBM - 1) / GBM)   // 782
#define WPAD 136                     // LDS W row pad (272B: 16B aligned, 2-way banks = free)

typedef _Float16 f16x8 __attribute__((ext_vector_type(8)));
typedef float    f32x4 __attribute__((ext_vector_type(4)));

// ---------------- pre: zero cnt + convert W0/W1 -> transposed fp16 ----------------
// blocks [0,49): zero cnt; [49,97): wt0[n*128+k] = W0[k*96+n]; [97,133): wt1[n*96+k] = W1[k*96+n]
__global__ __launch_bounds__(256) void pre_kernel(
    int4* __restrict__ cnt4, const float* __restrict__ W0, const float* __restrict__ W1,
    _Float16* __restrict__ wt0, _Float16* __restrict__ wt1)
{
    int b = blockIdx.x, t = threadIdx.x;
    if (b < 49) {
        int i = b * 256 + t;
        if (i < 12504) cnt4[i] = make_int4(0, 0, 0, 0);
    } else if (b < 97) {
        int idx = (b - 49) * 256 + t;          // idx = n*128+k (write-coalesced)
        int n = idx >> 7, k = idx & 127;
        wt0[idx] = (_Float16)W0[k * D_HID + n];
    } else {
        int idx = (b - 97) * 256 + t;          // idx = n*96+k
        int n = idx / 96, k = idx - n * 96;
        wt1[idx] = (_Float16)W1[k * D_HID + n];
    }
}

// ---------------- MFMA GEMM core: H = A[M,K] @ W[K,96] (fp16 in, fp32 acc) ------------
// Wave w: rows [bid*64+16w, +16) x 96 cols via 6 x mfma_f32_16x16x32_f16.
// Fragments (verified r7/m89): A row=lane&15, k=8*(lane>>4)+j; B col=lane&15 same k;
// D col=lane&15, row=4*(lane>>4)+r. W staged once (16B copies, one barrier); A-fragments
// loaded straight from global (row-local => OOB rows can't pollute valid rows).
__device__ __forceinline__ void gemm_alpha_mfma_body(
    const float* __restrict__ A, const _Float16* __restrict__ WT,
    const float* __restrict__ asrc, const float* __restrict__ adst,
    __half* __restrict__ Hout, float* __restrict__ aS, float* __restrict__ aD,
    int M, int K, int bid,
    _Float16 (*Wt)[WPAD], _Float16 (*Hl)[104], float* avl, float* adl)
{
    int tid  = threadIdx.x;
    int lane = tid & 63;
    int w    = tid >> 6;
    int n0   = bid * GBM;

    // stage WT [96][K] -> Wt[96][WPAD] as 16B chunks (conflict-free)
    int cpr = K >> 3;                 // 16B chunks per row
    int nch = 96 * cpr;
    for (int ch = tid; ch < nch; ch += 256) {
        int row = ch / cpr, off = (ch - row * cpr) << 3;
        *(f16x8*)&Wt[row][off] = *(const f16x8*)&WT[row * K + off];
    }
    if (tid < 96) { avl[tid] = asrc[tid]; adl[tid] = adst[tid]; }
    __syncthreads();

    int c  = lane & 15;
    int kg = lane >> 4;
    int arow = n0 + (w << 4) + c;
    const float* ap = A + (size_t)(arow < M ? arow : M - 1) * K + (kg << 3);

    f32x4 acc[6];
#pragma unroll
    for (int t = 0; t < 6; t++) acc[t] = (f32x4){0.f, 0.f, 0.f, 0.f};

    for (int k0 = 0; k0 < K; k0 += 32) {
        float4 a0 = *(const float4*)(ap + k0);
        float4 a1 = *(const float4*)(ap + k0 + 4);
        f16x8 av;
        av[0] = (_Float16)a0.x; av[1] = (_Float16)a0.y;
        av[2] = (_Float16)a0.z; av[3] = (_Float16)a0.w;
        av[4] = (_Float16)a1.x; av[5] = (_Float16)a1.y;
        av[6] = (_Float16)a1.z; av[7] = (_Float16)a1.w;
#pragma unroll
        for (int t = 0; t < 6; t++) {
            f16x8 bv = *(const f16x8*)&Wt[t * 16 + c][k0 + (kg << 3)];
            acc[t] = __builtin_amdgcn_mfma_f32_16x16x32_f16(av, bv, acc[t], 0, 0, 0);
        }
    }

    // D -> Hl (fp16): row = 16w + 4*kg + r, col = 16t + c  (static indices)
    int rbase = (w << 4) + (kg << 2);
#pragma unroll
    for (int t = 0; t < 6; t++)
#pragma unroll
        for (int r = 0; r < 4; r++)
            Hl[rbase + r][t * 16 + c] = (_Float16)acc[t][r];
    __syncthreads();

    // epilogue: thread (row=tid>>2, q=tid&3) owns cols [24q,24q+24) = heads 2q,2q+1
    int row = tid >> 2, q = tid & 3;
    int gr = n0 + row;
    if (gr < M) {
        float s0 = 0.f, s1 = 0.f, d0 = 0.f, d1 = 0.f;
#pragma unroll
        for (int j = 0; j < 12; j++) {
            float f = (float)Hl[row][q * 24 + j];
            s0 += f * avl[q * 24 + j];
            d0 += f * adl[q * 24 + j];
        }
#pragma unroll
        for (int j = 12; j < 24; j++) {
            float f = (float)Hl[row][q * 24 + j];
            s1 += f * avl[q * 24 + j];
            d1 += f * adl[q * 24 + j];
        }
        aS[gr * NHEAD + 2 * q]     = s0;
        aS[gr * NHEAD + 2 * q + 1] = s1;
        aD[gr * NHEAD + 2 * q]     = d0;
        aD[gr * NHEAD + 2 * q + 1] = d1;
        const uint4* src = (const uint4*)&Hl[row][q * 24];
        uint4* dst = (uint4*)(Hout + (size_t)gr * D_HID + q * 24);
        dst[0] = src[0]; dst[1] = src[1]; dst[2] = src[2];
    }
}

// ---------------- fused: hist (blocks [0,NHISTB)) + gemm0 (blocks [NHISTB,..)) --------
__global__ __launch_bounds__(256) void hist_gemm_kernel(
    const int* __restrict__ edst, int* __restrict__ cnt,
    const float* __restrict__ A, const _Float16* __restrict__ WT,
    const float* __restrict__ asrc, const float* __restrict__ adst,
    __half* __restrict__ Hout, float* __restrict__ aS, float* __restrict__ aD)
{
    __shared__ _Float16 Wt[D_HID][WPAD];
    __shared__ _Float16 Hl[GBM][104];
    __shared__ float avl[96], adl[96];
    if (blockIdx.x < NHISTB) {
        int lo = (blockIdx.x & 7) * NPART;   // bid&7 == XCD (round-robin dispatch)
        int e0 = (blockIdx.x >> 3) * ECHUNK;
        for (int e = e0 + threadIdx.x; e < e0 + ECHUNK; e += 256) {
            int d = edst[e] - lo;
            if ((unsigned)d < (unsigned)NPART) atomicAdd(&cnt[lo + d], 1);
        }
    } else {
        gemm_alpha_mfma_body(A, WT, asrc, adst, Hout, aS, aD, N_NODES, F_IN,
                             blockIdx.x - NHISTB, Wt, Hl, avl, adl);
    }
}

// ---------------- standalone gemm (layer 1, K=96) ----------------
__global__ __launch_bounds__(256) void gemm_alpha_kernel(
    const float* __restrict__ A, const _Float16* __restrict__ WT,
    const float* __restrict__ asrc, const float* __restrict__ adst,
    __half* __restrict__ Hout, float* __restrict__ aS, float* __restrict__ aD,
    int M, int K)
{
    __shared__ _Float16 Wt[D_HID][WPAD];
    __shared__ _Float16 Hl[GBM][104];
    __shared__ float avl[96], adl[96];
    gemm_alpha_mfma_body(A, WT, asrc, adst, Hout, aS, aD, M, K, blockIdx.x,
                         Wt, Hl, avl, adl);
}

// ---------------- scans ----------------
__global__ void scan1_kernel(const int* __restrict__ cnt, int* __restrict__ incl,
                             int* __restrict__ partials, int n) {
    __shared__ int sdata[256];
    int t = threadIdx.x;
    int base = blockIdx.x * 1024 + t * 4;
    int v[4];
#pragma unroll
    for (int j = 0; j < 4; j++) { int i = base + j; v[j] = (i < n) ? cnt[i] : 0; }
    v[1] += v[0]; v[2] += v[1]; v[3] += v[2];
    sdata[t] = v[3];
    __syncthreads();
    for (int off = 1; off < 256; off <<= 1) {
        int x = (t >= off) ? sdata[t - off] : 0;
        __syncthreads();
        sdata[t] += x;
        __syncthreads();
    }
    int excl = sdata[t] - v[3];
#pragma unroll
    for (int j = 0; j < 4; j++) { int i = base + j; if (i < n) incl[i] = v[j] + excl; }
    if (t == 255) partials[blockIdx.x] = sdata[255];
}

__global__ void scan3_kernel(const int* __restrict__ cnt, int* __restrict__ incl_cursor,
                             const int* __restrict__ partials, int* __restrict__ rowptr,
                             int n, int nb) {
    int i = blockIdx.x * blockDim.x + threadIdx.x;
    if (i >= n) return;
    int myb = i >> 10;
    int psum = 0;
    for (int b = 0; b < nb; b++) psum += (b < myb) ? partials[b] : 0;
    int v = incl_cursor[i] + psum;
    rowptr[i + 1] = v;
    incl_cursor[i] = v - cnt[i];
    if (i == 0) rowptr[0] = 0;
}

__global__ __launch_bounds__(256) void fill_part_kernel(
    const int* __restrict__ esrc, const int* __restrict__ edst,
    int* __restrict__ cursor, unsigned short* __restrict__ srclist)
{
    int lo = (blockIdx.x & 7) * NPART;
    int e0 = (blockIdx.x >> 3) * ECHUNK;
    for (int e = e0 + threadIdx.x; e < e0 + ECHUNK; e += 256) {
        int d = edst[e] - lo;
        if ((unsigned)d < (unsigned)NPART) {
            int p = atomicAdd(&cursor[lo + d], 1);
            srclist[p] = (unsigned short)esrc[e];
        }
    }
}

// ---------------- GAT aggregation: 16 lanes per node (2 per head) ----------------
__device__ __forceinline__ void agg_edge(const __half* __restrict__ h, int s, int hh,
                                         float p, float* acc) {
    const uint2* hp = (const uint2*)(h + (size_t)s * D_HID + hh * 12);
    uint2 q0 = hp[0], q1 = hp[1], q2 = hp[2];
    float2 f0 = __half22float2(((const __half2*)&q0)[0]);
    float2 f1 = __half22float2(((const __half2*)&q0)[1]);
    float2 f2 = __half22float2(((const __half2*)&q1)[0]);
    float2 f3 = __half22float2(((const __half2*)&q1)[1]);
    float2 f4 = __half22float2(((const __half2*)&q2)[0]);
    float2 f5 = __half22float2(((const __half2*)&q2)[1]);
    acc[0] += p * f0.x; acc[1]  += p * f0.y;
    acc[2] += p * f1.x; acc[3]  += p * f1.y;
    acc[4] += p * f2.x; acc[5]  += p * f2.y;
    acc[6] += p * f3.x; acc[7]  += p * f3.y;
    acc[8] += p * f4.x; acc[9]  += p * f4.y;
    acc[10] += p * f5.x; acc[11] += p * f5.y;
}

__device__ __forceinline__ float agg_half(
    const __half* __restrict__ h, const float* __restrict__ aS,
    const unsigned short* __restrict__ srclist,
    int b0, int b1, int hh, float ad, float* acc)
{
    float z = 0.f;
    int i = b0;
    for (; i + 4 <= b1; i += 4) {
        int sa = srclist[i];
        int sb = srclist[i + 1];
        int sc = srclist[i + 2];
        int sd = srclist[i + 3];
        float ea = aS[sa * NHEAD + hh] + ad;
        float eb = aS[sb * NHEAD + hh] + ad;
        float ec = aS[sc * NHEAD + hh] + ad;
        float ed = aS[sd * NHEAD + hh] + ad;
        ea = (ea > 0.f) ? ea : NEG_SLOPE * ea;
        eb = (eb > 0.f) ? eb : NEG_SLOPE * eb;
        ec = (ec > 0.f) ? ec : NEG_SLOPE * ec;
        ed = (ed > 0.f) ? ed : NEG_SLOPE * ed;
        float pa = __expf(ea);
        float pb = __expf(eb);
        float pc = __expf(ec);
        float pd = __expf(ed);
        z += (pa + pb) + (pc + pd);
        agg_edge(h, sa, hh, pa, acc);
        agg_edge(h, sb, hh, pb, acc);
        agg_edge(h, sc, hh, pc, acc);
        agg_edge(h, sd, hh, pd, acc);
    }
    for (; i < b1; i++) {
        int sa = srclist[i];
        float ea = aS[sa * NHEAD + hh] + ad;
        ea = (ea > 0.f) ? ea : NEG_SLOPE * ea;
        float pa = __expf(ea);
        z += pa;
        agg_edge(h, sa, hh, pa, acc);
    }
    return z;
}

// layer-0 aggregate -> bufY.  16 lanes/node: lane q = tid&15, head = q&7, half = q>>3.
__global__ __launch_bounds__(256) void gat_aggregate_kernel(
    const __half* __restrict__ h, const float* __restrict__ aS, const float* __restrict__ aD,
    const int* __restrict__ rowptr, const unsigned short* __restrict__ srclist,
    const float* __restrict__ bias, float* __restrict__ out)
{
    int gid  = blockIdx.x * 256 + threadIdx.x;
    int n    = gid >> 4;                 // grid exact: 50000*16 == 3125*256
    int q    = threadIdx.x & 15;
    int hh   = q & 7;
    int half = q >> 3;
    int s0 = rowptr[n], s1 = rowptr[n + 1];
    int mid = s0 + ((s1 - s0 + 1) >> 1);
    float ad = aD[n * NHEAD + hh];

    float acc[12];
#pragma unroll
    for (int j = 0; j < 12; j++) acc[j] = 0.f;
    float z = agg_half(h, aS, srclist, half ? mid : s0, half ? s1 : mid, hh, ad, acc);

    z += __shfl_xor(z, 8, 64);
#pragma unroll
    for (int j = 0; j < 12; j++) acc[j] += __shfl_xor(acc[j], 8, 64);

    if (half == 0) {
        float inv = 1.f / (z + 1e-16f);
        const float* bp = bias + hh * 12;
        float o[12];
#pragma unroll
        for (int j = 0; j < 12; j++) o[j] = acc[j] * inv + bp[j];
        float4* op = (float4*)(out + (size_t)n * D_HID + hh * 12);
        op[0] = make_float4(o[0], o[1], o[2], o[3]);
        op[1] = make_float4(o[4], o[5], o[6], o[7]);
        op[2] = make_float4(o[8], o[9], o[10], o[11]);
    }
}

// layer-1 aggregate + relu + (y @ Wout + bout) + log_softmax fused (LDS exchange;
// all register arrays statically indexed — rule #20).
#define YPAD 100
__global__ __launch_bounds__(256) void gat_aggregate_final_kernel(
    const __half* __restrict__ h, const float* __restrict__ aS, const float* __restrict__ aD,
    const int* __restrict__ rowptr, const unsigned short* __restrict__ srclist,
    const float* __restrict__ bias,
    const float* __restrict__ Wout, const float* __restrict__ bout,
    float* __restrict__ out)
{
    __shared__ float WsT[N_CLS][YPAD];   // WsT[c][r] = Wout[r*40+c]
    __shared__ float bs[N_CLS];
    __shared__ float ylds[16][YPAD];     // 16 nodes/block x 96-wide y
    for (int idx = threadIdx.x; idx < D_HID * N_CLS; idx += 256) {
        int r = idx / N_CLS, c = idx - r * N_CLS;
        WsT[c][r] = Wout[idx];
    }
    for (int idx = threadIdx.x; idx < N_CLS; idx += 256) bs[idx] = bout[idx];
    __syncthreads();

    int gid  = blockIdx.x * 256 + threadIdx.x;
    int n    = gid >> 4;
    int q    = threadIdx.x & 15;
    int hh   = q & 7;
    int half = q >> 3;
    int ln   = threadIdx.x >> 4;
    int s0 = rowptr[n], s1 = rowptr[n + 1];
    int mid = s0 + ((s1 - s0 + 1) >> 1);
    float ad = aD[n * NHEAD + hh];

    float acc[12];
#pragma unroll
    for (int j = 0; j < 12; j++) acc[j] = 0.f;
    float z = agg_half(h, aS, srclist, half ? mid : s0, half ? s1 : mid, hh, ad, acc);

    z += __shfl_xor(z, 8, 64);
#pragma unroll
    for (int j = 0; j < 12; j++) acc[j] += __shfl_xor(acc[j], 8, 64);

    if (half == 0) {
        float inv = 1.f / (z + 1e-16f);
        const float* bp = bias + hh * 12;
        float o[12];
#pragma unroll
        for (int j = 0; j < 12; j++) o[j] = fmaxf(acc[j] * inv + bp[j], 0.f);

        // publish y slice (same-wave producer/consumer: in-order DS, no barrier)
        float4* yw = (float4*)&ylds[ln][hh * 12];
        yw[0] = make_float4(o[0], o[1], o[2], o[3]);
        yw[1] = make_float4(o[4], o[5], o[6], o[7]);
        yw[2] = make_float4(o[8], o[9], o[10], o[11]);

        int c0 = hh * 5;
        float res[5];
#pragma unroll
        for (int k = 0; k < 5; k++) res[k] = bs[c0 + k];
        const float4* yr = (const float4*)&ylds[ln][0];
#pragma unroll
        for (int r4 = 0; r4 < D_HID / 4; r4++) {
            float4 yv = yr[r4];
#pragma unroll
            for (int k = 0; k < 5; k++) {
                float4 wv = *(const float4*)&WsT[c0 + k][r4 * 4];
                res[k] += yv.x * wv.x + yv.y * wv.y + yv.z * wv.z + yv.w * wv.w;
            }
        }

        float m = res[0];
#pragma unroll
        for (int k = 1; k < 5; k++) m = fmaxf(m, res[k]);
#pragma unroll
        for (int d = 1; d < 8; d <<= 1) m = fmaxf(m, __shfl_xor(m, d, 64));
        float sp = 0.f;
#pragma unroll
        for (int k = 0; k < 5; k++) sp += __expf(res[k] - m);
#pragma unroll
        for (int d = 1; d < 8; d <<= 1) sp += __shfl_xor(sp, d, 64);
        float mlg = m + __logf(sp);

        float* op = out + (size_t)n * N_CLS + c0;
#pragma unroll
        for (int k = 0; k < 5; k++) op[k] = res[k] - mlg;
    }
}

extern "C" void kernel_launch(void* const* d_in, const int* in_sizes, int n_in,
                              void* d_out, int out_size, void* d_ws, size_t ws_size,
                              hipStream_t stream)
{
    const float* x    = (const float*)d_in[0];
    const int*   esrc = (const int*)d_in[1];
    const int*   edst = (const int*)d_in[2];
    const float* W0   = (const float*)d_in[3];
    const float* as0  = (const float*)d_in[4];
    const float* ad0  = (const float*)d_in[5];
    const float* b0   = (const float*)d_in[6];
    const float* W1   = (const float*)d_in[7];
    const float* as1  = (const float*)d_in[8];
    const float* ad1  = (const float*)d_in[9];
    const float* b1   = (const float*)d_in[10];
    const float* Wout = (const float*)d_in[11];
    const float* bout = (const float*)d_in[12];
    float* out = (float*)d_out;

    char* p = (char*)d_ws;
    float* bufY   = (float*)p; p += (size_t)N_NODES * D_HID * sizeof(float);
    float* aS     = (float*)p; p += (size_t)N_NODES * NHEAD * sizeof(float);
    float* aD     = (float*)p; p += (size_t)N_NODES * NHEAD * sizeof(float);
    __half* bufH  = (__half*)p; p += (size_t)N_NODES * D_HID * sizeof(__half);
    int*   cnt    = (int*)p;   p += ((size_t)N_NODES + 16) * sizeof(int);
    int*   rowptr = (int*)p;   p += ((size_t)N_NODES + 16) * sizeof(int);
    int*   cursor = (int*)p;   p += ((size_t)N_NODES + 16) * sizeof(int);
    unsigned short* srclist = (unsigned short*)p; p += (size_t)N_EDGES * sizeof(unsigned short);
    int*   partials = (int*)p; p += 256;
    _Float16* wt0 = (_Float16*)p; p += (size_t)D_HID * F_IN * sizeof(_Float16);
    _Float16* wt1 = (_Float16*)p; p += (size_t)D_HID * D_HID * sizeof(_Float16);

    int nscan = (N_NODES + 1023) / 1024;   // 49

    // 1. zero cnt + fp16-transpose W0/W1 (one dispatch, grid-sliced)
    pre_kernel<<<133, 256, 0, stream>>>((int4*)cnt, W0, W1, wt0, wt1);
    // 2. hist (XCD-partitioned) + MFMA gemm0 fused by grid-slicing
    hist_gemm_kernel<<<NHISTB + NGB, 256, 0, stream>>>(
        edst, cnt, x, wt0, as0, ad0, bufH, aS, aD);
    // 3-4. scan
    scan1_kernel<<<nscan, 256, 0, stream>>>(cnt, cursor, partials, N_NODES);
    scan3_kernel<<<(N_NODES + 255) / 256, 256, 0, stream>>>(cnt, cursor, partials, rowptr,
                                                            N_NODES, nscan);
    // 5. fill CSR
    fill_part_kernel<<<NHISTB, 256, 0, stream>>>(esrc, edst, cursor, srclist);
    // 6. layer-0 aggregate -> bufY (16 lanes/node)
    gat_aggregate_kernel<<<(N_NODES * 16) / 256, 256, 0, stream>>>(
        bufH, aS, aD, rowptr, srclist, b0, bufY);
    // 7. layer-1 MFMA gemm (K=96)
    gemm_alpha_kernel<<<NGB, 256, 0, stream>>>(
        bufY, wt1, as1, ad1, bufH, aS, aD, N_NODES, D_HID);
    // 8. layer-1 aggregate + relu + output linear + log_softmax -> out
    gat_aggregate_final_kernel<<<(N_NODES * 16) / 256, 256, 0, stream>>>(
        bufH, aS, aD, rowptr, srclist, b1, Wout, bout, out);
}